// Round 2
// baseline (3572.429 us; speedup 1.0000x reference)
//
#include <hip/hip_runtime.h>
#include <hip/hip_bf16.h>

// order-preserving encode for float atomicMax on uint
__device__ inline unsigned int fenc(float f) {
    unsigned int b = __float_as_uint(f);
    return (b & 0x80000000u) ? ~b : (b | 0x80000000u);
}
__device__ inline float fdec(unsigned int u) {
    unsigned int b = (u & 0x80000000u) ? (u & 0x7FFFFFFFu) : ~u;
    return __uint_as_float(b);
}

// ---------------- K1: q/k/v = xin @ W + b  (W is [L,128] f32) ----------------
template <int L>
__global__ __launch_bounds__(256) void qkv_kernel(
    const float* __restrict__ xin,
    const float* __restrict__ wq, const float* __restrict__ bq,
    const float* __restrict__ wk, const float* __restrict__ bk,
    const float* __restrict__ wv, const float* __restrict__ bv,
    float* __restrict__ q, float* __restrict__ k, float* __restrict__ v, int N)
{
    __shared__ float xs[16][L + 1];
    const int tid = threadIdx.x;
    const int node0 = blockIdx.x * 16;
    for (int i = tid; i < 16 * L; i += 256) {
        int nb = i / L, l = i - nb * L;
        int n = node0 + nb;
        xs[nb][l] = (n < N) ? xin[(long)n * L + l] : 0.f;
    }
    __syncthreads();
    const int nb = tid >> 4;        // node within block (0..15)
    const int j0 = (tid & 15) * 8;  // 8 output columns
    const int n = node0 + nb;
    float aq[8], ak[8], av[8];
#pragma unroll
    for (int i = 0; i < 8; i += 4) {
        *(float4*)(aq + i) = *(const float4*)(bq + j0 + i);
        *(float4*)(ak + i) = *(const float4*)(bk + j0 + i);
        *(float4*)(av + i) = *(const float4*)(bv + j0 + i);
    }
    for (int l = 0; l < L; ++l) {
        float xv = xs[nb][l];
        float wqf[8], wkf[8], wvf[8];
#pragma unroll
        for (int i = 0; i < 8; i += 4) {
            *(float4*)(wqf + i) = *(const float4*)(wq + l * 128 + j0 + i);
            *(float4*)(wkf + i) = *(const float4*)(wk + l * 128 + j0 + i);
            *(float4*)(wvf + i) = *(const float4*)(wv + l * 128 + j0 + i);
        }
#pragma unroll
        for (int i = 0; i < 8; i++) {
            aq[i] += xv * wqf[i]; ak[i] += xv * wkf[i]; av[i] += xv * wvf[i];
        }
    }
    if (n < N) {
        long base = (long)n * 128 + j0;
#pragma unroll
        for (int i = 0; i < 8; i += 4) {
            *(float4*)(q + base + i) = *(float4*)(aq + i);
            *(float4*)(k + base + i) = *(float4*)(ak + i);
            *(float4*)(v + base + i) = *(float4*)(av + i);
        }
    }
}

// ---------------- K2: per-edge logits + segment max ----------------
__global__ __launch_bounds__(256) void edge_logits_kernel(
    const float* __restrict__ q, const float* __restrict__ k,
    const int* __restrict__ src, const int* __restrict__ dst,
    float* __restrict__ logits, unsigned int* __restrict__ m, int E)
{
    int gid = blockIdx.x * blockDim.x + threadIdx.x;
    int e = gid >> 5, t = gid & 31;
    if (e >= E) return;
    int s = src[e], d = dst[e];
    float4 qv = *(const float4*)(q + (long)d * 128 + t * 4);
    float4 kv = *(const float4*)(k + (long)s * 128 + t * 4);
    float p = qv.x * kv.x + qv.y * kv.y + qv.z * kv.z + qv.w * kv.w;
    p += __shfl_down(p, 4, 8);
    p += __shfl_down(p, 2, 8);
    p += __shfl_down(p, 1, 8);
    if ((t & 7) == 0) {
        int h = t >> 3;
        float logit = p * 0.17677669529663687f;  // 1/sqrt(32)
        logits[(long)e * 4 + h] = logit;
        atomicMax(&m[d * 4 + h], fenc(logit));
    }
}

// ---------------- K3: e = exp(logit - m[dst]); denom += e ----------------
__global__ __launch_bounds__(256) void edge_exp_kernel(
    float* __restrict__ logits, const unsigned int* __restrict__ m,
    const int* __restrict__ dst, float* __restrict__ denom, int E)
{
    int gid = blockIdx.x * blockDim.x + threadIdx.x;
    if (gid >= E * 4) return;
    int e = gid >> 2, h = gid & 3;
    int d = dst[e];
    float mx = fdec(m[d * 4 + h]);
    // reference: m = where(isfinite(m), m, 0)
    if (!isfinite(mx)) mx = 0.f;
    float ev = __expf(logits[gid] - mx);
    logits[gid] = ev;
    atomicAdd(&denom[d * 4 + h], ev);
}

// ---------------- K4: agg[dst] += alpha * v[src] ----------------
__global__ __launch_bounds__(256) void edge_scatter_kernel(
    const float* __restrict__ v, const float* __restrict__ eV,
    const float* __restrict__ denom,
    const int* __restrict__ src, const int* __restrict__ dst,
    float* __restrict__ agg, int E)
{
    int gid = blockIdx.x * blockDim.x + threadIdx.x;
    int e = gid >> 5, t = gid & 31;
    if (e >= E) return;
    int s = src[e], d = dst[e];
    int h = t >> 3;
    float alpha = eV[(long)e * 4 + h] / (denom[d * 4 + h] + 1e-16f);
    float4 vv = *(const float4*)(v + (long)s * 128 + t * 4);
    float* ap = agg + (long)d * 128 + t * 4;
    atomicAdd(ap + 0, alpha * vv.x);
    atomicAdd(ap + 1, alpha * vv.y);
    atomicAdd(ap + 2, alpha * vv.z);
    atomicAdd(ap + 3, alpha * vv.w);
}

// ---------------- K5: out = relu(mean_h(agg) + xin @ ws + bs) ----------------
template <int L>
__global__ __launch_bounds__(256) void finalize_kernel(
    const float* __restrict__ agg, const float* __restrict__ xin,
    const float* __restrict__ ws, const float* __restrict__ bs,
    float* __restrict__ out, int N)
{
    int gid = blockIdx.x * blockDim.x + threadIdx.x;
    int n = gid >> 5, j = gid & 31;
    if (n >= N) return;
    float skip = bs[j];
    for (int l = 0; l < L; ++l)
        skip += xin[(long)n * L + l] * ws[l * 32 + j];
    const float* ar = agg + (long)n * 128;
    float mean = 0.25f * (ar[j] + ar[32 + j] + ar[64 + j] + ar[96 + j]);
    float r = mean + skip;
    out[(long)n * 32 + j] = r > 0.f ? r : 0.f;
}

// ---------------- K6: final classifier [N,32] @ [32,40] + bc ----------------
__global__ __launch_bounds__(256) void classify_kernel(
    const float* __restrict__ h, const float* __restrict__ wc,
    const float* __restrict__ bc, float* __restrict__ out, int N)
{
    int gid = blockIdx.x * blockDim.x + threadIdx.x;
    if (gid >= N * 40) return;
    int n = gid / 40, o = gid - (gid / 40) * 40;
    float acc = bc[o];
    const float* hr = h + (long)n * 32;
#pragma unroll
    for (int l = 0; l < 32; ++l) acc += hr[l] * wc[l * 40 + o];
    out[gid] = acc;
}

extern "C" void kernel_launch(void* const* d_in, const int* in_sizes, int n_in,
                              void* d_out, int out_size, void* d_ws, size_t ws_size,
                              hipStream_t stream)
{
    const float* x   = (const float*)d_in[0];
    const int* ei    = (const int*)d_in[1];
    const float* wq1 = (const float*)d_in[2];  const float* bq1 = (const float*)d_in[3];
    const float* wk1 = (const float*)d_in[4];  const float* bk1 = (const float*)d_in[5];
    const float* wv1 = (const float*)d_in[6];  const float* bv1 = (const float*)d_in[7];
    const float* ws1 = (const float*)d_in[8];  const float* bs1 = (const float*)d_in[9];
    const float* wq2 = (const float*)d_in[10]; const float* bq2 = (const float*)d_in[11];
    const float* wk2 = (const float*)d_in[12]; const float* bk2 = (const float*)d_in[13];
    const float* wv2 = (const float*)d_in[14]; const float* bv2 = (const float*)d_in[15];
    const float* ws2 = (const float*)d_in[16]; const float* bs2 = (const float*)d_in[17];
    const float* wc  = (const float*)d_in[18]; const float* bc  = (const float*)d_in[19];

    const int N = in_sizes[0] / 128;   // 50000
    const int E = in_sizes[1] / 2;     // 800000
    const int* src = ei;
    const int* dst = ei + E;

    // workspace layout (agg aliases q: q is dead after edge_logits)
    float* q     = (float*)d_ws;            // N*128
    float* agg   = q;                       // alias
    float* k     = q + (long)N * 128;       // N*128
    float* v     = k + (long)N * 128;       // N*128
    float* eV    = v + (long)N * 128;       // E*4
    unsigned int* m = (unsigned int*)(eV + (long)E * 4);  // N*4
    float* denom = (float*)(m + (long)N * 4);             // N*4
    float* h1    = denom + (long)N * 4;     // N*32
    float* h2    = h1 + (long)N * 32;       // N*32

    const int qkvGrid  = (N + 15) / 16;
    const int edgeGrid = (E * 32 + 255) / 256;
    const int expGrid  = (E * 4 + 255) / 256;
    const int finGrid  = (N * 32 + 255) / 256;

    // ---------------- layer 1 ----------------
    hipMemsetAsync(m, 0, (size_t)N * 4 * 4, stream);
    hipMemsetAsync(denom, 0, (size_t)N * 4 * 4, stream);
    qkv_kernel<128><<<qkvGrid, 256, 0, stream>>>(x, wq1, bq1, wk1, bk1, wv1, bv1, q, k, v, N);
    edge_logits_kernel<<<edgeGrid, 256, 0, stream>>>(q, k, src, dst, eV, m, E);
    hipMemsetAsync(agg, 0, (size_t)N * 128 * 4, stream);  // q dead now; agg aliases q
    edge_exp_kernel<<<expGrid, 256, 0, stream>>>(eV, m, dst, denom, E);
    edge_scatter_kernel<<<edgeGrid, 256, 0, stream>>>(v, eV, denom, src, dst, agg, E);
    finalize_kernel<128><<<finGrid, 256, 0, stream>>>(agg, x, ws1, bs1, h1, N);

    // ---------------- layer 2 ----------------
    hipMemsetAsync(m, 0, (size_t)N * 4 * 4, stream);
    hipMemsetAsync(denom, 0, (size_t)N * 4 * 4, stream);
    qkv_kernel<32><<<qkvGrid, 256, 0, stream>>>(h1, wq2, bq2, wk2, bk2, wv2, bv2, q, k, v, N);
    edge_logits_kernel<<<edgeGrid, 256, 0, stream>>>(q, k, src, dst, eV, m, E);
    hipMemsetAsync(agg, 0, (size_t)N * 128 * 4, stream);
    edge_exp_kernel<<<expGrid, 256, 0, stream>>>(eV, m, dst, denom, E);
    edge_scatter_kernel<<<edgeGrid, 256, 0, stream>>>(v, eV, denom, src, dst, agg, E);
    finalize_kernel<32><<<finGrid, 256, 0, stream>>>(agg, h1, ws2, bs2, h2, N);

    // ---------------- classifier ----------------
    classify_kernel<<<(N * 40 + 255) / 256, 256, 0, stream>>>(h2, wc, bc, (float*)d_out, N);
}

// Round 3
// 944.049 us; speedup vs baseline: 3.7842x; 3.7842x over previous
//
#include <hip/hip_runtime.h>
#include <hip/hip_bf16.h>

// ---------------- CSR build ----------------
__global__ __launch_bounds__(256) void hist_kernel(
    const int* __restrict__ dst, int* __restrict__ deg, int E)
{
    int e = blockIdx.x * blockDim.x + threadIdx.x;
    if (e < E) atomicAdd(&deg[dst[e]], 1);
}

// single-workgroup inclusive-scan -> exclusive rowptr + cursor copy
__global__ __launch_bounds__(1024) void scan_kernel(
    const int* __restrict__ deg, int* __restrict__ rowptr,
    int* __restrict__ cursor, int N)
{
    __shared__ int buf[1024];
    __shared__ int carry;
    if (threadIdx.x == 0) carry = 0;
    __syncthreads();
    for (int base = 0; base < N; base += 1024) {
        int i = base + threadIdx.x;
        int val = (i < N) ? deg[i] : 0;
        buf[threadIdx.x] = val;
        __syncthreads();
        for (int off = 1; off < 1024; off <<= 1) {
            int t = (threadIdx.x >= off) ? buf[threadIdx.x - off] : 0;
            __syncthreads();
            buf[threadIdx.x] += t;
            __syncthreads();
        }
        int exc = buf[threadIdx.x] - val + carry;
        if (i < N) { rowptr[i] = exc; cursor[i] = exc; }
        __syncthreads();
        if (threadIdx.x == 1023) carry += buf[1023];
        __syncthreads();
    }
    if (threadIdx.x == 0) rowptr[N] = carry;
}

__global__ __launch_bounds__(256) void fill_kernel(
    const int* __restrict__ src, const int* __restrict__ dst,
    int* __restrict__ cursor, int* __restrict__ perm, int E)
{
    int e = blockIdx.x * blockDim.x + threadIdx.x;
    if (e >= E) return;
    int pos = atomicAdd(&cursor[dst[e]], 1);
    perm[pos] = src[e];
}

// ---------------- K1: q/k/v = xin @ W + b  (W is [L,128] f32) ----------------
template <int L>
__global__ __launch_bounds__(256) void qkv_kernel(
    const float* __restrict__ xin,
    const float* __restrict__ wq, const float* __restrict__ bq,
    const float* __restrict__ wk, const float* __restrict__ bk,
    const float* __restrict__ wv, const float* __restrict__ bv,
    float* __restrict__ q, float* __restrict__ k, float* __restrict__ v, int N)
{
    __shared__ float xs[16][L + 1];
    const int tid = threadIdx.x;
    const int node0 = blockIdx.x * 16;
    for (int i = tid; i < 16 * L; i += 256) {
        int nb = i / L, l = i - nb * L;
        int n = node0 + nb;
        xs[nb][l] = (n < N) ? xin[(long)n * L + l] : 0.f;
    }
    __syncthreads();
    const int nb = tid >> 4;        // node within block (0..15)
    const int j0 = (tid & 15) * 8;  // 8 output columns
    const int n = node0 + nb;
    float aq[8], ak[8], av[8];
#pragma unroll
    for (int i = 0; i < 8; i += 4) {
        *(float4*)(aq + i) = *(const float4*)(bq + j0 + i);
        *(float4*)(ak + i) = *(const float4*)(bk + j0 + i);
        *(float4*)(av + i) = *(const float4*)(bv + j0 + i);
    }
    for (int l = 0; l < L; ++l) {
        float xv = xs[nb][l];
        float wqf[8], wkf[8], wvf[8];
#pragma unroll
        for (int i = 0; i < 8; i += 4) {
            *(float4*)(wqf + i) = *(const float4*)(wq + l * 128 + j0 + i);
            *(float4*)(wkf + i) = *(const float4*)(wk + l * 128 + j0 + i);
            *(float4*)(wvf + i) = *(const float4*)(wv + l * 128 + j0 + i);
        }
#pragma unroll
        for (int i = 0; i < 8; i++) {
            aq[i] += xv * wqf[i]; ak[i] += xv * wkf[i]; av[i] += xv * wvf[i];
        }
    }
    if (n < N) {
        long base = (long)n * 128 + j0;
#pragma unroll
        for (int i = 0; i < 8; i += 4) {
            *(float4*)(q + base + i) = *(float4*)(aq + i);
            *(float4*)(k + base + i) = *(float4*)(ak + i);
            *(float4*)(v + base + i) = *(float4*)(av + i);
        }
    }
}

// ---------------- K2: fused per-node online-softmax attention ----------------
// one wave per dst node; lane l owns dims {2l, 2l+1}; head = l>>4.
__global__ __launch_bounds__(256) void attn_kernel(
    const float* __restrict__ q, const float* __restrict__ k,
    const float* __restrict__ v, const int* __restrict__ rowptr,
    const int* __restrict__ perm, float* __restrict__ aggm, int N)
{
    const int wid = (blockIdx.x * 256 + threadIdx.x) >> 6;
    const int lane = threadIdx.x & 63;
    if (wid >= N) return;
    const int d = wid;
    const float2 q2 = *(const float2*)(q + (long)d * 128 + lane * 2);
    float m = -INFINITY, den = 0.f;
    float ox = 0.f, oy = 0.f;
    const int beg = rowptr[d], end = rowptr[d + 1];
    const float scale = 0.17677669529663687f;  // 1/sqrt(32)
    int idx = beg;
    for (; idx + 1 < end; idx += 2) {
        int s0 = perm[idx], s1 = perm[idx + 1];
        const float2 k0 = *(const float2*)(k + (long)s0 * 128 + lane * 2);
        const float2 k1 = *(const float2*)(k + (long)s1 * 128 + lane * 2);
        const float2 v0 = *(const float2*)(v + (long)s0 * 128 + lane * 2);
        const float2 v1 = *(const float2*)(v + (long)s1 * 128 + lane * 2);
        float p0 = q2.x * k0.x + q2.y * k0.y;
        float p1 = q2.x * k1.x + q2.y * k1.y;
        p0 += __shfl_xor(p0, 1);  p1 += __shfl_xor(p1, 1);
        p0 += __shfl_xor(p0, 2);  p1 += __shfl_xor(p1, 2);
        p0 += __shfl_xor(p0, 4);  p1 += __shfl_xor(p1, 4);
        p0 += __shfl_xor(p0, 8);  p1 += __shfl_xor(p1, 8);
        float l0 = p0 * scale, l1 = p1 * scale;
        // edge 0
        float nm = fmaxf(m, l0);
        float sc = __expf(m - nm);
        float w  = __expf(l0 - nm);
        den = den * sc + w;
        ox = ox * sc + w * v0.x;
        oy = oy * sc + w * v0.y;
        m = nm;
        // edge 1
        nm = fmaxf(m, l1);
        sc = __expf(m - nm);
        w  = __expf(l1 - nm);
        den = den * sc + w;
        ox = ox * sc + w * v1.x;
        oy = oy * sc + w * v1.y;
        m = nm;
    }
    if (idx < end) {
        int s0 = perm[idx];
        const float2 k0 = *(const float2*)(k + (long)s0 * 128 + lane * 2);
        const float2 v0 = *(const float2*)(v + (long)s0 * 128 + lane * 2);
        float p0 = q2.x * k0.x + q2.y * k0.y;
        p0 += __shfl_xor(p0, 1);
        p0 += __shfl_xor(p0, 2);
        p0 += __shfl_xor(p0, 4);
        p0 += __shfl_xor(p0, 8);
        float l0 = p0 * scale;
        float nm = fmaxf(m, l0);
        float sc = __expf(m - nm);
        float w  = __expf(l0 - nm);
        den = den * sc + w;
        ox = ox * sc + w * v0.x;
        oy = oy * sc + w * v0.y;
    }
    float inv = 1.f / (den + 1e-16f);
    ox *= inv; oy *= inv;
    // mean over 4 heads: lanes {l, l^16, l^32, l^48} hold same channel
    ox += __shfl_xor(ox, 16); oy += __shfl_xor(oy, 16);
    ox += __shfl_xor(ox, 32); oy += __shfl_xor(oy, 32);
    if (lane < 16) {
        float2 r = make_float2(0.25f * ox, 0.25f * oy);
        *(float2*)(aggm + (long)d * 32 + lane * 2) = r;
    }
}

// ---------------- K3: out = relu(aggm + xin @ ws + bs) ----------------
template <int L>
__global__ __launch_bounds__(256) void finalize_kernel(
    const float* __restrict__ aggm, const float* __restrict__ xin,
    const float* __restrict__ ws, const float* __restrict__ bs,
    float* __restrict__ out, int N)
{
    int gid = blockIdx.x * blockDim.x + threadIdx.x;
    int n = gid >> 5, j = gid & 31;
    if (n >= N) return;
    float skip = bs[j];
    for (int l = 0; l < L; ++l)
        skip += xin[(long)n * L + l] * ws[l * 32 + j];
    float r = aggm[(long)n * 32 + j] + skip;
    out[(long)n * 32 + j] = r > 0.f ? r : 0.f;
}

// ---------------- K4: final classifier [N,32] @ [32,40] + bc ----------------
__global__ __launch_bounds__(256) void classify_kernel(
    const float* __restrict__ h, const float* __restrict__ wc,
    const float* __restrict__ bc, float* __restrict__ out, int N)
{
    int gid = blockIdx.x * blockDim.x + threadIdx.x;
    if (gid >= N * 40) return;
    int n = gid / 40, o = gid - (gid / 40) * 40;
    float acc = bc[o];
    const float* hr = h + (long)n * 32;
#pragma unroll
    for (int l = 0; l < 32; ++l) acc += hr[l] * wc[l * 40 + o];
    out[gid] = acc;
}

extern "C" void kernel_launch(void* const* d_in, const int* in_sizes, int n_in,
                              void* d_out, int out_size, void* d_ws, size_t ws_size,
                              hipStream_t stream)
{
    const float* x   = (const float*)d_in[0];
    const int* ei    = (const int*)d_in[1];
    const float* wq1 = (const float*)d_in[2];  const float* bq1 = (const float*)d_in[3];
    const float* wk1 = (const float*)d_in[4];  const float* bk1 = (const float*)d_in[5];
    const float* wv1 = (const float*)d_in[6];  const float* bv1 = (const float*)d_in[7];
    const float* ws1 = (const float*)d_in[8];  const float* bs1 = (const float*)d_in[9];
    const float* wq2 = (const float*)d_in[10]; const float* bq2 = (const float*)d_in[11];
    const float* wk2 = (const float*)d_in[12]; const float* bk2 = (const float*)d_in[13];
    const float* wv2 = (const float*)d_in[14]; const float* bv2 = (const float*)d_in[15];
    const float* ws2 = (const float*)d_in[16]; const float* bs2 = (const float*)d_in[17];
    const float* wc  = (const float*)d_in[18]; const float* bc  = (const float*)d_in[19];

    const int N = in_sizes[0] / 128;   // 50000
    const int E = in_sizes[1] / 2;     // 800000
    const int* src = ei;
    const int* dst = ei + E;

    // workspace layout
    float* q    = (float*)d_ws;            // N*128
    float* k    = q + (long)N * 128;       // N*128
    float* v    = k + (long)N * 128;       // N*128
    float* aggm = v + (long)N * 128;       // N*32
    float* h1   = aggm + (long)N * 32;     // N*32
    float* h2   = h1 + (long)N * 32;       // N*32
    int* deg    = (int*)(h2 + (long)N * 32); // N
    int* rowptr = deg + N;                 // N+1
    int* cursor = rowptr + N + 1;          // N
    int* perm   = cursor + N;              // E

    const int qkvGrid  = (N + 15) / 16;
    const int eGrid    = (E + 255) / 256;
    const int attnGrid = (N + 3) / 4;          // 4 waves/block
    const int finGrid  = (N * 32 + 255) / 256;

    // ---------------- CSR build (once; reused by both layers) ----------------
    hipMemsetAsync(deg, 0, (size_t)N * 4, stream);
    hist_kernel<<<eGrid, 256, 0, stream>>>(dst, deg, E);
    scan_kernel<<<1, 1024, 0, stream>>>(deg, rowptr, cursor, N);
    fill_kernel<<<eGrid, 256, 0, stream>>>(src, dst, cursor, perm, E);

    // ---------------- layer 1 ----------------
    qkv_kernel<128><<<qkvGrid, 256, 0, stream>>>(x, wq1, bq1, wk1, bk1, wv1, bv1, q, k, v, N);
    attn_kernel<<<attnGrid, 256, 0, stream>>>(q, k, v, rowptr, perm, aggm, N);
    finalize_kernel<128><<<finGrid, 256, 0, stream>>>(aggm, x, ws1, bs1, h1, N);

    // ---------------- layer 2 ----------------
    qkv_kernel<32><<<qkvGrid, 256, 0, stream>>>(h1, wq2, bq2, wk2, bk2, wv2, bv2, q, k, v, N);
    attn_kernel<<<attnGrid, 256, 0, stream>>>(q, k, v, rowptr, perm, aggm, N);
    finalize_kernel<32><<<finGrid, 256, 0, stream>>>(aggm, h1, ws2, bs2, h2, N);

    // ---------------- classifier ----------------
    classify_kernel<<<(N * 40 + 255) / 256, 256, 0, stream>>>(h2, wc, bc, (float*)d_out, N);
}

// Round 4
// 649.240 us; speedup vs baseline: 5.5025x; 1.4541x over previous
//
#include <hip/hip_runtime.h>
#include <hip/hip_bf16.h>

// ---------------- CSR build ----------------
__global__ __launch_bounds__(256) void hist_kernel(
    const int* __restrict__ dst, int* __restrict__ deg, int E)
{
    int e = blockIdx.x * blockDim.x + threadIdx.x;
    if (e < E) atomicAdd(&deg[dst[e]], 1);
}

// single-workgroup scan, wave-shfl based (few barriers)
__global__ __launch_bounds__(1024) void scan_kernel(
    const int* __restrict__ deg, int* __restrict__ rowptr,
    int* __restrict__ cursor, int N)
{
    __shared__ int wsum[16];
    __shared__ int wpre[16];
    __shared__ int chunk_total;
    __shared__ int carry_s;
    const int tid = threadIdx.x, wave = tid >> 6, lane = tid & 63;
    if (tid == 0) carry_s = 0;
    __syncthreads();
    for (int base = 0; base < N; base += 1024) {
        int i = base + tid;
        int val = (i < N) ? deg[i] : 0;
        int inc = val;
#pragma unroll
        for (int off = 1; off < 64; off <<= 1) {
            int t = __shfl_up(inc, off, 64);
            if (lane >= off) inc += t;
        }
        if (lane == 63) wsum[wave] = inc;
        __syncthreads();
        if (wave == 0) {
            int s = (lane < 16) ? wsum[lane] : 0;
#pragma unroll
            for (int off = 1; off < 16; off <<= 1) {
                int t = __shfl_up(s, off, 64);
                if (lane >= off) s += t;
            }
            if (lane < 16) wpre[lane] = s - wsum[lane];
            if (lane == 15) chunk_total = s;
        }
        __syncthreads();
        int exc = carry_s + wpre[wave] + inc - val;
        if (i < N) { rowptr[i] = exc; cursor[i] = exc; }
        __syncthreads();
        if (tid == 0) carry_s += chunk_total;
        __syncthreads();
    }
    if (tid == 0) rowptr[N] = carry_s;
}

__global__ __launch_bounds__(256) void fill_kernel(
    const int* __restrict__ src, const int* __restrict__ dst,
    int* __restrict__ cursor, int* __restrict__ perm, int E)
{
    int e = blockIdx.x * blockDim.x + threadIdx.x;
    if (e >= E) return;
    int pos = atomicAdd(&cursor[dst[e]], 1);
    perm[pos] = src[e];
}

// ---------------- K1: fused projection q/k/v/skip ----------------
// Block: 256 threads = 4 waves, 32 nodes. Waves 0..2 -> q/k/v (lane owns 2 of
// 128 cols, weights in registers reused across 32 nodes, x broadcast from LDS).
// Wave 3 -> skip = x @ ws + bs (col = lane&31, 16 nodes per lane-half).
template <int L>
__global__ __launch_bounds__(256) void proj_kernel(
    const float* __restrict__ xin,
    const float* __restrict__ wq, const float* __restrict__ bq,
    const float* __restrict__ wk, const float* __restrict__ bk,
    const float* __restrict__ wv, const float* __restrict__ bv,
    const float* __restrict__ ws, const float* __restrict__ bs,
    float* __restrict__ q, float* __restrict__ k, float* __restrict__ v,
    float* __restrict__ skip, int N)
{
    __shared__ float xs[32 * L];
    const int tid = threadIdx.x, wave = tid >> 6, lane = tid & 63;
    const int n0 = blockIdx.x * 32;
    constexpr int L4 = L / 4;
    for (int idx = tid; idx < 32 * L4; idx += 256) {
        int row = idx / L4, c4 = idx - row * L4;
        int n = n0 + row;
        float4 val = (n < N) ? *(const float4*)(xin + (long)n * L + c4 * 4)
                             : make_float4(0.f, 0.f, 0.f, 0.f);
        *(float4*)(xs + row * L + c4 * 4) = val;
    }
    __syncthreads();

    if (wave < 3) {
        const float* w = (wave == 0) ? wq : ((wave == 1) ? wk : wv);
        const float* b = (wave == 0) ? bq : ((wave == 1) ? bk : bv);
        float* o       = (wave == 0) ? q  : ((wave == 1) ? k  : v);
        const float2 bias = *(const float2*)(b + lane * 2);
        float2 acc[32];
#pragma unroll
        for (int n = 0; n < 32; n++) acc[n] = bias;
        for (int kk = 0; kk < L; kk += 2) {
            float2 w0 = *(const float2*)(w + kk * 128 + lane * 2);
            float2 w1 = *(const float2*)(w + (kk + 1) * 128 + lane * 2);
#pragma unroll
            for (int n = 0; n < 32; n++) {
                float2 xv = *(const float2*)(xs + n * L + kk);
                acc[n].x = fmaf(xv.y, w1.x, fmaf(xv.x, w0.x, acc[n].x));
                acc[n].y = fmaf(xv.y, w1.y, fmaf(xv.x, w0.y, acc[n].y));
            }
        }
#pragma unroll
        for (int n = 0; n < 32; n++) {
            if (n0 + n < N)
                *(float2*)(o + (long)(n0 + n) * 128 + lane * 2) = acc[n];
        }
    } else {
        const int col = lane & 31;
        const int nb0 = (lane >> 5) * 16;
        float accs[16];
        float bsv = bs[col];
#pragma unroll
        for (int i = 0; i < 16; i++) accs[i] = bsv;
        for (int kk = 0; kk < L; kk++) {
            float wv_ = ws[kk * 32 + col];
#pragma unroll
            for (int i = 0; i < 16; i++)
                accs[i] = fmaf(xs[(nb0 + i) * L + kk], wv_, accs[i]);
        }
#pragma unroll
        for (int i = 0; i < 16; i++) {
            int n = n0 + nb0 + i;
            if (n < N) skip[(long)n * 32 + col] = accs[i];
        }
    }
}

// ---------------- K2: fused per-node online-softmax attention ----------------
// one wave per dst node; lane l owns dims {2l, 2l+1}; head = l>>4.
__global__ __launch_bounds__(256) void attn_kernel(
    const float* __restrict__ q, const float* __restrict__ k,
    const float* __restrict__ v, const int* __restrict__ rowptr,
    const int* __restrict__ perm, float* __restrict__ aggm, int N)
{
    const int wid = (blockIdx.x * 256 + threadIdx.x) >> 6;
    const int lane = threadIdx.x & 63;
    if (wid >= N) return;
    const int d = wid;
    const float2 q2 = *(const float2*)(q + (long)d * 128 + lane * 2);
    float m = -INFINITY, den = 0.f;
    float ox = 0.f, oy = 0.f;
    const int beg = rowptr[d], end = rowptr[d + 1];
    const float scale = 0.17677669529663687f;  // 1/sqrt(32)
    int idx = beg;
    for (; idx + 1 < end; idx += 2) {
        int s0 = perm[idx], s1 = perm[idx + 1];
        const float2 k0 = *(const float2*)(k + (long)s0 * 128 + lane * 2);
        const float2 k1 = *(const float2*)(k + (long)s1 * 128 + lane * 2);
        const float2 v0 = *(const float2*)(v + (long)s0 * 128 + lane * 2);
        const float2 v1 = *(const float2*)(v + (long)s1 * 128 + lane * 2);
        float p0 = q2.x * k0.x + q2.y * k0.y;
        float p1 = q2.x * k1.x + q2.y * k1.y;
        p0 += __shfl_xor(p0, 1);  p1 += __shfl_xor(p1, 1);
        p0 += __shfl_xor(p0, 2);  p1 += __shfl_xor(p1, 2);
        p0 += __shfl_xor(p0, 4);  p1 += __shfl_xor(p1, 4);
        p0 += __shfl_xor(p0, 8);  p1 += __shfl_xor(p1, 8);
        float l0 = p0 * scale, l1 = p1 * scale;
        float nm = fmaxf(m, l0);
        float sc = __expf(m - nm);
        float w  = __expf(l0 - nm);
        den = den * sc + w;
        ox = ox * sc + w * v0.x;
        oy = oy * sc + w * v0.y;
        m = nm;
        nm = fmaxf(m, l1);
        sc = __expf(m - nm);
        w  = __expf(l1 - nm);
        den = den * sc + w;
        ox = ox * sc + w * v1.x;
        oy = oy * sc + w * v1.y;
        m = nm;
    }
    if (idx < end) {
        int s0 = perm[idx];
        const float2 k0 = *(const float2*)(k + (long)s0 * 128 + lane * 2);
        const float2 v0 = *(const float2*)(v + (long)s0 * 128 + lane * 2);
        float p0 = q2.x * k0.x + q2.y * k0.y;
        p0 += __shfl_xor(p0, 1);
        p0 += __shfl_xor(p0, 2);
        p0 += __shfl_xor(p0, 4);
        p0 += __shfl_xor(p0, 8);
        float l0 = p0 * scale;
        float nm = fmaxf(m, l0);
        float sc = __expf(m - nm);
        float w  = __expf(l0 - nm);
        den = den * sc + w;
        ox = ox * sc + w * v0.x;
        oy = oy * sc + w * v0.y;
    }
    float inv = 1.f / (den + 1e-16f);
    ox *= inv; oy *= inv;
    ox += __shfl_xor(ox, 16); oy += __shfl_xor(oy, 16);
    ox += __shfl_xor(ox, 32); oy += __shfl_xor(oy, 32);
    if (lane < 16) {
        float2 r = make_float2(0.25f * ox, 0.25f * oy);
        *(float2*)(aggm + (long)d * 32 + lane * 2) = r;
    }
}

// ---------------- K3: out = relu(aggm + skip)  (skip already has bias) -------
__global__ __launch_bounds__(256) void finalize_kernel(
    const float* __restrict__ aggm, const float* __restrict__ skip,
    float* __restrict__ out, int total)
{
    int gid = blockIdx.x * blockDim.x + threadIdx.x;
    if (gid >= total) return;
    float r = aggm[gid] + skip[gid];
    out[gid] = r > 0.f ? r : 0.f;
}

// ---------------- K4: final classifier [N,32] @ [32,40] + bc ----------------
__global__ __launch_bounds__(256) void classify_kernel(
    const float* __restrict__ h, const float* __restrict__ wc,
    const float* __restrict__ bc, float* __restrict__ out, int N)
{
    int gid = blockIdx.x * blockDim.x + threadIdx.x;
    if (gid >= N * 40) return;
    int n = gid / 40, o = gid - (gid / 40) * 40;
    float acc = bc[o];
    const float* hr = h + (long)n * 32;
#pragma unroll
    for (int l = 0; l < 32; ++l) acc += hr[l] * wc[l * 40 + o];
    out[gid] = acc;
}

extern "C" void kernel_launch(void* const* d_in, const int* in_sizes, int n_in,
                              void* d_out, int out_size, void* d_ws, size_t ws_size,
                              hipStream_t stream)
{
    const float* x   = (const float*)d_in[0];
    const int* ei    = (const int*)d_in[1];
    const float* wq1 = (const float*)d_in[2];  const float* bq1 = (const float*)d_in[3];
    const float* wk1 = (const float*)d_in[4];  const float* bk1 = (const float*)d_in[5];
    const float* wv1 = (const float*)d_in[6];  const float* bv1 = (const float*)d_in[7];
    const float* ws1 = (const float*)d_in[8];  const float* bs1 = (const float*)d_in[9];
    const float* wq2 = (const float*)d_in[10]; const float* bq2 = (const float*)d_in[11];
    const float* wk2 = (const float*)d_in[12]; const float* bk2 = (const float*)d_in[13];
    const float* wv2 = (const float*)d_in[14]; const float* bv2 = (const float*)d_in[15];
    const float* ws2 = (const float*)d_in[16]; const float* bs2 = (const float*)d_in[17];
    const float* wc  = (const float*)d_in[18]; const float* bc  = (const float*)d_in[19];

    const int N = in_sizes[0] / 128;   // 50000
    const int E = in_sizes[1] / 2;     // 800000
    const int* src = ei;
    const int* dst = ei + E;

    // workspace layout
    float* q    = (float*)d_ws;            // N*128
    float* k    = q + (long)N * 128;       // N*128
    float* v    = k + (long)N * 128;       // N*128
    float* aggm = v + (long)N * 128;       // N*32
    float* skip = aggm + (long)N * 32;     // N*32
    float* h1   = skip + (long)N * 32;     // N*32
    float* h2   = h1 + (long)N * 32;       // N*32
    int* deg    = (int*)(h2 + (long)N * 32); // N
    int* rowptr = deg + N;                 // N+1
    int* cursor = rowptr + N + 1;          // N
    int* perm   = cursor + N;              // E

    const int projGrid = (N + 31) / 32;
    const int eGrid    = (E + 255) / 256;
    const int attnGrid = (N + 3) / 4;          // 4 waves/block
    const int finGrid  = (N * 32 + 255) / 256;

    // ---------------- CSR build (once; reused by both layers) ----------------
    hipMemsetAsync(deg, 0, (size_t)N * 4, stream);
    hist_kernel<<<eGrid, 256, 0, stream>>>(dst, deg, E);
    scan_kernel<<<1, 1024, 0, stream>>>(deg, rowptr, cursor, N);
    fill_kernel<<<eGrid, 256, 0, stream>>>(src, dst, cursor, perm, E);

    // ---------------- layer 1 ----------------
    proj_kernel<128><<<projGrid, 256, 0, stream>>>(x, wq1, bq1, wk1, bk1, wv1, bv1,
                                                   ws1, bs1, q, k, v, skip, N);
    attn_kernel<<<attnGrid, 256, 0, stream>>>(q, k, v, rowptr, perm, aggm, N);
    finalize_kernel<<<finGrid, 256, 0, stream>>>(aggm, skip, h1, N * 32);

    // ---------------- layer 2 ----------------
    proj_kernel<32><<<projGrid, 256, 0, stream>>>(h1, wq2, bq2, wk2, bk2, wv2, bv2,
                                                  ws2, bs2, q, k, v, skip, N);
    attn_kernel<<<attnGrid, 256, 0, stream>>>(q, k, v, rowptr, perm, aggm, N);
    finalize_kernel<<<finGrid, 256, 0, stream>>>(aggm, skip, h2, N * 32);

    // ---------------- classifier ----------------
    classify_kernel<<<(N * 40 + 255) / 256, 256, 0, stream>>>(h2, wc, bc, (float*)d_out, N);
}